// Round 5
// baseline (235.050 us; speedup 1.0000x reference)
//
#include <hip/hip_runtime.h>
#include <math.h>

#define NN 512

#define C1 0.06154574548966636f   // 1/sqrt(264)
#define C2 0.08838834764831845f   // 1/sqrt(128)
#define SQRT3 1.7320508075688772f

typedef __attribute__((ext_vector_type(8))) short bf16x8;   // 8 bf16 = 4 VGPRs
typedef __attribute__((ext_vector_type(4))) float f32x4;

#define MFMA16 __builtin_amdgcn_mfma_f32_16x16x32_bf16
// pack two fp32 -> one u32 of 2 bf16 (lo = a, hi = b)
#define CVT_PK(dst, a, b) asm("v_cvt_pk_bf16_f32 %0, %1, %2" : "=v"(dst) : "v"(a), "v"(b))

__device__ __forceinline__ float silu_f(float x) {
    float e = __builtin_amdgcn_exp2f(x * -1.442695041f);
    return x * __builtin_amdgcn_rcpf(1.0f + e);
}
__device__ __forceinline__ float sigm_f(float x) {
    float e = __builtin_amdgcn_exp2f(x * -1.442695041f);
    return __builtin_amdgcn_rcpf(1.0f + e);
}
__device__ __forceinline__ short f2bf(float f) {
    unsigned u = __builtin_bit_cast(unsigned, f);
    u = (u + 0x7FFFu + ((u >> 16) & 1u)) >> 16;
    return (short)u;
}

// ---------------------------------------------------------------------------
// k_pack: [K=128 x ncols] fp32 -> bf16 frags. Frag (ct,kt), lane l, elem j
// holds W[32kt + (l>>4)*8 + j][16ct + (l&15)]. Serves BOTH as B-frag of W and
// as A-frag of W^T (identical index formula).
// ---------------------------------------------------------------------------
__global__ __launch_bounds__(256)
void k_pack(const float* __restrict__ W, short* __restrict__ out, int ncols)
{
    int idx = blockIdx.x * 256 + threadIdx.x;
    int lane = idx & 63, kt = (idx >> 6) & 3, ct = idx >> 8;
    if (ct * 16 >= ncols) return;
    int g = lane >> 4, c = lane & 15;
    bf16x8 v;
    #pragma unroll
    for (int j = 0; j < 8; ++j)
        v[j] = f2bf(W[(kt * 32 + g * 8 + j) * ncols + ct * 16 + c]);
    *(bf16x8*)(out + (size_t)idx * 8) = v;
}

// ---------------------------------------------------------------------------
// k_packL: A-frags of We1-length block (k<8 rows of We1, transposed), K padded
// to 32 (k>=8 zero). 8 frags (rt). Also packs Winf into (g,rt,jj) order.
// ---------------------------------------------------------------------------
__global__ __launch_bounds__(512)
void k_packL(const float* __restrict__ We1, const float* __restrict__ Winf,
             short* __restrict__ outL, float* __restrict__ Winfp)
{
    int t = threadIdx.x;               // 0..511 = rt*64 + lane
    int rt = t >> 6, l = t & 63, g = l >> 4, c = l & 15;
    bf16x8 v = {0,0,0,0,0,0,0,0};
    if (g == 0) {
        #pragma unroll
        for (int j = 0; j < 8; ++j)
            v[j] = f2bf(We1[j * 128 + rt * 16 + c]);
    }
    *(bf16x8*)(outL + (size_t)t * 8) = v;
    if (t < 128) {
        int u = t;
        Winfp[((u >> 2) & 3) * 32 + (u >> 4) * 4 + (u & 3)] = Winf[u];
    }
}

// ---------------------------------------------------------------------------
// k_proj: FsP plain; FrP packed into D-order f32: FrPp[n][g*32+rt*4+jj],
// u = 4g + 16rt + jj.
// ---------------------------------------------------------------------------
__global__ __launch_bounds__(128)
void k_proj(const float* __restrict__ feat, const float* __restrict__ We1,
            float* __restrict__ FsP, float* __restrict__ FrPp)
{
    __shared__ float sF[128];
    int n = blockIdx.x, j = threadIdx.x;
    sF[j] = feat[n * 128 + j];
    __syncthreads();
    float a = 0.f, b = 0.f;
    #pragma unroll 8
    for (int k = 0; k < 128; ++k) {
        float f = sF[k];
        a = fmaf(f, We1[(8   + k) * 128 + j], a);
        b = fmaf(f, We1[(136 + k) * 128 + j], b);
    }
    FsP[n * 128 + j] = a;
    FrPp[n * 128 + ((j >> 2) & 3) * 32 + (j >> 4) * 4 + (j & 3)] = b;
}

// ---------------------------------------------------------------------------
// k_edge: one block per sender, 4 waves, each wave owns 128 receivers
// (4 iters x 32), NO barriers in the main loop. Swapped-operand MFMA:
// D[u][recv] = Wpack(A) @ act^T(B). D: col=lane&15=recv, row u=16rt+4g+jj.
// ---------------------------------------------------------------------------
__global__ __launch_bounds__(256, 2)
void k_edge(const float* __restrict__ pos,
            const float* __restrict__ FsP,
            const float* __restrict__ FrPp,
            const float* __restrict__ Winfp,
            const short* __restrict__ We1Lp,
            const short* __restrict__ We2p,
            const short* __restrict__ Wx1p,
            const short* __restrict__ Wx2p,
            const short* __restrict__ Wtpp,
            float* __restrict__ MI,
            float* __restrict__ VEC)
{
    __shared__ __align__(16) short sAct[4 * 4096];  // per-wave [32][128] bf16, swizzled
    __shared__ __align__(16) float sSh[4 * 1024];   // per-wave [32][8] f32x4 (sh.xyz,len)
    __shared__ float sFsPl[128];                    // FsP[s] packed (g,rt,jj)
    __shared__ float sWinf[128];                    // Winf packed (g,rt,jj)
    __shared__ float sPosS[24];
    __shared__ float sMiP[512];                     // per-wave mi partials
    __shared__ float sVp[96];                       // per-wave vec partials

    const int s = blockIdx.x, t = threadIdx.x;
    const int lane = t & 63, w = t >> 6;
    const int rl = lane & 15, g = lane >> 4;

    if (t < 128) {
        int u = t;
        sFsPl[((u >> 2) & 3) * 32 + (u >> 4) * 4 + (u & 3)] = FsP[s * 128 + u];
        sWinf[t] = Winfp[t];
    }
    if (t < 24) sPosS[t] = pos[s * 24 + t];
    __syncthreads();                                            // only init barrier

    char* myAct = (char*)sAct + w * 8192;
    char* mySh  = (char*)sSh  + w * 4096;
    const char* cFsP  = (const char*)sFsPl;
    const char* cWinf = (const char*)sWinf;

    const bf16x8* pL   = (const bf16x8*)We1Lp;
    const bf16x8* pWe2 = (const bf16x8*)We2p;
    const bf16x8* pWx1 = (const bf16x8*)Wx1p;
    const bf16x8* pWx2 = (const bf16x8*)Wx2p;
    const bf16x8* pWtp = (const bf16x8*)Wtpp;

    float miacc[32];
    float vacc[12];
    #pragma unroll
    for (int q = 0; q < 32; ++q) miacc[q] = 0.f;
    #pragma unroll
    for (int q = 0; q < 12; ++q) vacc[q] = 0.f;

    const f32x4 z4 = {0.f, 0.f, 0.f, 0.f};

    for (int it = 0; it < 4; ++it) {
        const int r0 = w * 128 + it * 32;
        const int n0 = r0 + rl, n1 = n0 + 16;

        // ---------- ph0: sh + len -> wave-private sSh ----------
        #pragma unroll
        for (int ct = 0; ct < 2; ++ct) {
            int r = ct * 16 + rl, node = r0 + r;
            const float* pp = pos + (size_t)node * 24 + g * 6;
            float dx0 = sPosS[g*6+0] - pp[0];
            float dy0 = sPosS[g*6+1] - pp[1];
            float dz0 = sPosS[g*6+2] - pp[2];
            float dx1 = sPosS[g*6+3] - pp[3];
            float dy1 = sPosS[g*6+4] - pp[4];
            float dz1 = sPosS[g*6+5] - pp[5];
            float l0 = sqrtf(fmaxf(dx0*dx0 + dy0*dy0 + dz0*dz0, 1e-20f));
            float l1 = sqrtf(fmaxf(dx1*dx1 + dy1*dy1 + dz1*dz1, 1e-20f));
            float i0 = SQRT3 / l0, i1 = SQRT3 / l1;
            f32x4 o0; o0[0] = dx0*i0; o0[1] = dy0*i0; o0[2] = dz0*i0; o0[3] = l0;
            f32x4 o1; o1[0] = dx1*i1; o1[1] = dy1*i1; o1[2] = dz1*i1; o1[3] = l1;
            int v0 = 2 * g;
            *(f32x4*)(mySh + ((r*8 + (v0     ^ (r&7))) * 16)) = o0;
            *(f32x4*)(mySh + ((r*8 + ((v0+1) ^ (r&7))) * 16)) = o1;
        }

        // ---------- L1: B = lens (k<8), A = We1Lp; + FsP + FrP, silu ----------
        bf16x8 bL[2] = {{0,0,0,0,0,0,0,0}, {0,0,0,0,0,0,0,0}};
        if (g == 0) {
            #pragma unroll
            for (int ct = 0; ct < 2; ++ct) {
                int r = ct * 16 + rl;
                float L[8];
                #pragma unroll
                for (int j = 0; j < 8; ++j)
                    L[j] = *(const float*)(mySh + ((r*8 + (j ^ (r&7))) * 16) + 12);
                unsigned u01, u23, u45, u67;
                CVT_PK(u01, L[0], L[1]); CVT_PK(u23, L[2], L[3]);
                CVT_PK(u45, L[4], L[5]); CVT_PK(u67, L[6], L[7]);
                uint4 q = {u01, u23, u45, u67};
                bL[ct] = __builtin_bit_cast(bf16x8, q);
            }
        }
        bf16x8 A1[8];
        #pragma unroll
        for (int rt = 0; rt < 8; ++rt) A1[rt] = pL[rt * 64 + lane];

        f32x4 acc[8][2];
        #pragma unroll
        for (int rt = 0; rt < 8; ++rt) {
            acc[rt][0] = MFMA16(A1[rt], bL[0], z4, 0, 0, 0);
            acc[rt][1] = MFMA16(A1[rt], bL[1], z4, 0, 0, 0);
        }
        #pragma unroll
        for (int ct = 0; ct < 2; ++ct) {
            int node = ct ? n1 : n0;
            int r = ct * 16 + rl;
            f32x4 fr[8];
            #pragma unroll
            for (int rt = 0; rt < 8; ++rt)
                fr[rt] = *(const f32x4*)(FrPp + (size_t)node * 128 + g * 32 + rt * 4);
            #pragma unroll
            for (int rt = 0; rt < 8; ++rt) {
                f32x4 fs = *(const f32x4*)(cFsP + (g * 32 + rt * 4) * 4);
                float v0 = silu_f((acc[rt][ct][0] + fs[0] + fr[rt][0]) * C1);
                float v1 = silu_f((acc[rt][ct][1] + fs[1] + fr[rt][1]) * C1);
                float v2 = silu_f((acc[rt][ct][2] + fs[2] + fr[rt][2]) * C1);
                float v3 = silu_f((acc[rt][ct][3] + fs[3] + fr[rt][3]) * C1);
                unsigned p01, p23;
                CVT_PK(p01, v0, v1);
                CVT_PK(p23, v2, v3);
                int fb = 8 * g + 32 * rt;
                *(unsigned*)(myAct + (r*256 + ((fb    ) ^ ((r&7)<<4)))) = p01;
                *(unsigned*)(myAct + (r*256 + ((fb + 4) ^ ((r&7)<<4)))) = p23;
            }
        }

        // ---------- L2: m = silu(C2 * act @ We2); e; mi; write back ----------
        bf16x8 bA[2][4];
        #pragma unroll
        for (int ct = 0; ct < 2; ++ct) {
            int r = ct * 16 + rl;
            #pragma unroll
            for (int kt = 0; kt < 4; ++kt)
                bA[ct][kt] = *(const bf16x8*)(myAct + (r*256 + ((64*kt + 16*g) ^ ((r&7)<<4))));
        }
        #pragma unroll
        for (int rt = 0; rt < 8; ++rt) { acc[rt][0] = z4; acc[rt][1] = z4; }
        #pragma unroll
        for (int kt = 0; kt < 4; ++kt) {
            bf16x8 a[8];
            #pragma unroll
            for (int rt = 0; rt < 8; ++rt) a[rt] = pWe2[(rt * 4 + kt) * 64 + lane];
            #pragma unroll
            for (int rt = 0; rt < 8; ++rt) {
                acc[rt][0] = MFMA16(a[rt], bA[0][kt], acc[rt][0], 0, 0, 0);
                acc[rt][1] = MFMA16(a[rt], bA[1][kt], acc[rt][1], 0, 0, 0);
            }
        }
        float d0 = 0.f, d1 = 0.f;
        #pragma unroll
        for (int rt = 0; rt < 8; ++rt) {
            f32x4 wi = *(const f32x4*)(cWinf + (g * 32 + rt * 4) * 4);
            #pragma unroll
            for (int jj = 0; jj < 4; ++jj) {
                float m0 = silu_f(acc[rt][0][jj] * C2);
                float m1 = silu_f(acc[rt][1][jj] * C2);
                acc[rt][0][jj] = m0; acc[rt][1][jj] = m1;
                d0 = fmaf(m0, wi[jj], d0);
                d1 = fmaf(m1, wi[jj], d1);
            }
        }
        d0 += __shfl_xor(d0, 16); d0 += __shfl_xor(d0, 32);
        d1 += __shfl_xor(d1, 16); d1 += __shfl_xor(d1, 32);
        float e0 = (n0 == s) ? 0.f : sigm_f(d0 * C2);
        float e1 = (n1 == s) ? 0.f : sigm_f(d1 * C2);
        #pragma unroll
        for (int rt = 0; rt < 8; ++rt)
            #pragma unroll
            for (int jj = 0; jj < 4; ++jj)
                miacc[rt * 4 + jj] = fmaf(acc[rt][0][jj], e0,
                                     fmaf(acc[rt][1][jj], e1, miacc[rt * 4 + jj]));
        #pragma unroll
        for (int ct = 0; ct < 2; ++ct) {
            int r = ct * 16 + rl;
            #pragma unroll
            for (int rt = 0; rt < 8; ++rt) {
                unsigned p01, p23;
                CVT_PK(p01, acc[rt][ct][0], acc[rt][ct][1]);
                CVT_PK(p23, acc[rt][ct][2], acc[rt][ct][3]);
                int fb = 8 * g + 32 * rt;
                *(unsigned*)(myAct + (r*256 + ((fb    ) ^ ((r&7)<<4)))) = p01;
                *(unsigned*)(myAct + (r*256 + ((fb + 4) ^ ((r&7)<<4)))) = p23;
            }
        }

        // ---------- L3, L4: phi_x MLP ----------
        #pragma unroll
        for (int layer = 0; layer < 2; ++layer) {
            const bf16x8* pw = layer ? pWx2 : pWx1;
            #pragma unroll
            for (int ct = 0; ct < 2; ++ct) {
                int r = ct * 16 + rl;
                #pragma unroll
                for (int kt = 0; kt < 4; ++kt)
                    bA[ct][kt] = *(const bf16x8*)(myAct + (r*256 + ((64*kt + 16*g) ^ ((r&7)<<4))));
            }
            #pragma unroll
            for (int rt = 0; rt < 8; ++rt) { acc[rt][0] = z4; acc[rt][1] = z4; }
            #pragma unroll
            for (int kt = 0; kt < 4; ++kt) {
                bf16x8 a[8];
                #pragma unroll
                for (int rt = 0; rt < 8; ++rt) a[rt] = pw[(rt * 4 + kt) * 64 + lane];
                #pragma unroll
                for (int rt = 0; rt < 8; ++rt) {
                    acc[rt][0] = MFMA16(a[rt], bA[0][kt], acc[rt][0], 0, 0, 0);
                    acc[rt][1] = MFMA16(a[rt], bA[1][kt], acc[rt][1], 0, 0, 0);
                }
            }
            #pragma unroll
            for (int ct = 0; ct < 2; ++ct) {
                int r = ct * 16 + rl;
                #pragma unroll
                for (int rt = 0; rt < 8; ++rt) {
                    float v0 = silu_f(acc[rt][ct][0] * C2);
                    float v1 = silu_f(acc[rt][ct][1] * C2);
                    float v2 = silu_f(acc[rt][ct][2] * C2);
                    float v3 = silu_f(acc[rt][ct][3] * C2);
                    unsigned p01, p23;
                    CVT_PK(p01, v0, v1);
                    CVT_PK(p23, v2, v3);
                    int fb = 8 * g + 32 * rt;
                    *(unsigned*)(myAct + (r*256 + ((fb    ) ^ ((r&7)<<4)))) = p01;
                    *(unsigned*)(myAct + (r*256 + ((fb + 4) ^ ((r&7)<<4)))) = p23;
                }
            }
        }

        // ---------- TP: g = phi @ Wtp (64 cols), vec acc ----------
        #pragma unroll
        for (int ct = 0; ct < 2; ++ct) {
            int r = ct * 16 + rl;
            #pragma unroll
            for (int kt = 0; kt < 4; ++kt)
                bA[ct][kt] = *(const bf16x8*)(myAct + (r*256 + ((64*kt + 16*g) ^ ((r&7)<<4))));
        }
        f32x4 tacc[4][2];
        #pragma unroll
        for (int rt = 0; rt < 4; ++rt) { tacc[rt][0] = z4; tacc[rt][1] = z4; }
        #pragma unroll
        for (int kt = 0; kt < 4; ++kt) {
            bf16x8 a[4];
            #pragma unroll
            for (int rt = 0; rt < 4; ++rt) a[rt] = pWtp[(rt * 4 + kt) * 64 + lane];
            #pragma unroll
            for (int rt = 0; rt < 4; ++rt) {
                tacc[rt][0] = MFMA16(a[rt], bA[0][kt], tacc[rt][0], 0, 0, 0);
                tacc[rt][1] = MFMA16(a[rt], bA[1][kt], tacc[rt][1], 0, 0, 0);
            }
        }
        #pragma unroll
        for (int rt = 0; rt < 4; ++rt) {
            int v = 2 * rt + (g >> 1);
            #pragma unroll
            for (int ct = 0; ct < 2; ++ct) {
                int r = ct * 16 + rl;
                f32x4 sh = *(const f32x4*)(mySh + ((r*8 + (v ^ (r&7))) * 16));
                #pragma unroll
                for (int jj = 0; jj < 4; ++jj) {
                    float gg = tacc[rt][ct][jj];
                    vacc[jj*3+0] = fmaf(gg, sh[0], vacc[jj*3+0]);
                    vacc[jj*3+1] = fmaf(gg, sh[1], vacc[jj*3+1]);
                    vacc[jj*3+2] = fmaf(gg, sh[2], vacc[jj*3+2]);
                }
            }
        }
    }

    // ---------- end reductions ----------
    #pragma unroll
    for (int q = 0; q < 32; ++q) {
        float v = miacc[q];
        v += __shfl_xor(v, 1); v += __shfl_xor(v, 2);
        v += __shfl_xor(v, 4); v += __shfl_xor(v, 8);
        if (rl == 0) sMiP[w * 128 + g * 32 + q] = v;
    }
    #pragma unroll
    for (int q = 0; q < 12; ++q) {
        float v = vacc[q];
        v += __shfl_xor(v, 1); v += __shfl_xor(v, 2);
        v += __shfl_xor(v, 4); v += __shfl_xor(v, 8);
        v += __shfl_xor(v, 32);
        if (rl == 0 && g < 2) sVp[w * 24 + g * 12 + q] = v;
    }
    __syncthreads();
    if (t < 128) {
        int u = t;
        int pk = ((u >> 2) & 3) * 32 + (u >> 4) * 4 + (u & 3);
        MI[s * 128 + u] = sMiP[pk] + sMiP[128 + pk] + sMiP[256 + pk] + sMiP[384 + pk];
    }
    if (t < 24) {
        int wv = t / 3, kc = t - wv * 3;
        int g01 = wv >> 2, jj = wv & 3;
        int o = g01 * 12 + jj * 3 + kc;
        float sum = sVp[o] + sVp[24 + o] + sVp[48 + o] + sVp[72 + o];
        VEC[s * 24 + t] = sum * (1.0f / 32.0f);
    }
}

// ---------------------------------------------------------------------------
// k_node: per-node h-MLP + residual + position update.
// ---------------------------------------------------------------------------
__global__ __launch_bounds__(128)
void k_node(const float* __restrict__ pos, const float* __restrict__ feat,
            const float* __restrict__ Wh1, const float* __restrict__ Wh2,
            const float* __restrict__ Wh3,
            const float* __restrict__ MI, const float* __restrict__ VEC,
            float* __restrict__ outPos, float* __restrict__ outFeat)
{
    __shared__ float sMi[128], sF[128], sH[128];
    int n = blockIdx.x, j = threadIdx.x;
    sMi[j] = MI[n * 128 + j];
    sF[j]  = feat[n * 128 + j];
    __syncthreads();
    float a = 0.f;
    #pragma unroll 8
    for (int k = 0; k < 128; ++k) a = fmaf(sMi[k], Wh1[k * 128 + j], a);
    #pragma unroll 8
    for (int k = 0; k < 128; ++k) a = fmaf(sF[k], Wh1[(128 + k) * 128 + j], a);
    a = silu_f(a * 0.0625f);            // 1/sqrt(256)
    sH[j] = a;
    __syncthreads();
    float b = 0.f;
    #pragma unroll 8
    for (int k = 0; k < 128; ++k) b = fmaf(sH[k], Wh2[k * 128 + j], b);
    b = silu_f(b * C2);
    sMi[j] = b;
    __syncthreads();
    float cc = 0.f;
    #pragma unroll 8
    for (int k = 0; k < 128; ++k) cc = fmaf(sMi[k], Wh3[k * 128 + j], cc);
    outFeat[n * 128 + j] = cc * C2 + sF[j];
    if (j < 24) outPos[n * 24 + j] = pos[n * 24 + j] + VEC[n * 24 + j];
}

// ---------------------------------------------------------------------------
extern "C" void kernel_launch(void* const* d_in, const int* in_sizes, int n_in,
                              void* d_out, int out_size, void* d_ws, size_t ws_size,
                              hipStream_t stream) {
    const float* pos  = (const float*)d_in[0];
    const float* feat = (const float*)d_in[1];
    const float* We1  = (const float*)d_in[2];
    const float* We2  = (const float*)d_in[3];
    const float* Wx1  = (const float*)d_in[4];
    const float* Wx2  = (const float*)d_in[5];
    const float* Winf = (const float*)d_in[6];
    const float* Wtp  = (const float*)d_in[7];
    const float* Wh1  = (const float*)d_in[8];
    const float* Wh2  = (const float*)d_in[9];
    const float* Wh3  = (const float*)d_in[10];

    float* outPos  = (float*)d_out;              // [512*8*3]
    float* outFeat = (float*)d_out + NN * 24;    // [512*128]

    float* ws    = (float*)d_ws;
    float* FsP   = ws;                   // 65536 floats
    float* FrPp  = ws + 65536;           // 65536 (packed D-order f32)
    float* MI    = ws + 131072;          // 65536
    float* VEC   = ws + 196608;          // 12288
    float* Winfp = ws + 208896;          // 128
    short* wpack = (short*)(ws + 209024);
    short* We2p  = wpack;                // 16384 shorts
    short* Wx1p  = wpack + 16384;        // 16384
    short* Wx2p  = wpack + 32768;        // 16384
    short* Wtpp  = wpack + 49152;        // 8192
    short* We1Lp = wpack + 57344;        // 4096   (total ws ~959 KB)

    k_pack<<<dim3(8), dim3(256), 0, stream>>>(We2, We2p, 128);
    k_pack<<<dim3(8), dim3(256), 0, stream>>>(Wx1, Wx1p, 128);
    k_pack<<<dim3(8), dim3(256), 0, stream>>>(Wx2, Wx2p, 128);
    k_pack<<<dim3(4), dim3(256), 0, stream>>>(Wtp, Wtpp, 64);
    k_packL<<<dim3(1), dim3(512), 0, stream>>>(We1, Winf, We1Lp, Winfp);
    k_proj<<<dim3(NN), dim3(128), 0, stream>>>(feat, We1, FsP, FrPp);
    k_edge<<<dim3(NN), dim3(256), 0, stream>>>(pos, FsP, FrPp, Winfp,
                                               We1Lp, We2p, Wx1p, Wx2p, Wtpp, MI, VEC);
    k_node<<<dim3(NN), dim3(128), 0, stream>>>(pos, feat, Wh1, Wh2, Wh3, MI, VEC,
                                               outPos, outFeat);
}

// Round 6
// 123.264 us; speedup vs baseline: 1.9069x; 1.9069x over previous
//
#include <hip/hip_runtime.h>
#include <math.h>

#define NN   512
#define NV   8
#define CH   32      // receivers per chunk
#define NCHH 8       // chunks per half-block (2 blocks per sender)

#define C1 0.06154574548966636f   // 1/sqrt(264)
#define C2 0.08838834764831845f   // 1/sqrt(128)
#define SQRT3 1.7320508075688772f

typedef __attribute__((ext_vector_type(8))) short bf16x8;   // 8 bf16 = 4 VGPRs
typedef __attribute__((ext_vector_type(4))) float f32x4;

#define MFMA16 __builtin_amdgcn_mfma_f32_16x16x32_bf16
// pack two fp32 -> one u32 of 2 bf16 (lo = a, hi = b)
#define CVT_PK(dst, a, b) asm("v_cvt_pk_bf16_f32 %0, %1, %2" : "=v"(dst) : "v"(a), "v"(b))

__device__ __forceinline__ float silu_f(float x) {
    float e = __builtin_amdgcn_exp2f(x * -1.442695041f);
    return x * __builtin_amdgcn_rcpf(1.0f + e);
}
__device__ __forceinline__ float sigm_f(float x) {
    float e = __builtin_amdgcn_exp2f(x * -1.442695041f);
    return __builtin_amdgcn_rcpf(1.0f + e);
}
__device__ __forceinline__ short f2bf(float f) {
    unsigned u = __builtin_bit_cast(unsigned, f);
    u = (u + 0x7FFFu + ((u >> 16) & 1u)) >> 16;
    return (short)u;
}
__device__ __forceinline__ float bfhi(unsigned u) {
    return __builtin_bit_cast(float, u & 0xFFFF0000u);
}
__device__ __forceinline__ float bflo(unsigned u) {
    return __builtin_bit_cast(float, u << 16);
}

// ---------------------------------------------------------------------------
// k_pack: [128 x ncols] fp32 -> bf16 B-frags. Frag (ct,kt), lane l, elem j
// holds W[32kt + (l>>4)*8 + j][16ct + (l&15)].
// ---------------------------------------------------------------------------
__global__ __launch_bounds__(256)
void k_pack(const float* __restrict__ W, short* __restrict__ out, int ncols)
{
    int idx = blockIdx.x * 256 + threadIdx.x;
    int lane = idx & 63, kt = (idx >> 6) & 3, ct = idx >> 8;
    if (ct * 16 >= ncols) return;
    int g = lane >> 4, c = lane & 15;
    bf16x8 v;
    #pragma unroll
    for (int j = 0; j < 8; ++j)
        v[j] = f2bf(W[(kt * 32 + g * 8 + j) * ncols + ct * 16 + c]);
    *(bf16x8*)(out + (size_t)idx * 8) = v;
}

// ---------------------------------------------------------------------------
// k_packL: B-frags of We1 length rows (k<8), K padded to 32 (k>=8 zero).
// 8 col-tiles (ct). outL[(ct*64+l)*8+j].
// ---------------------------------------------------------------------------
__global__ __launch_bounds__(512)
void k_packL(const float* __restrict__ We1, short* __restrict__ outL)
{
    int t = threadIdx.x;               // 0..511 = ct*64 + lane
    int ct = t >> 6, l = t & 63, g = l >> 4, c = l & 15;
    bf16x8 v = {0,0,0,0,0,0,0,0};
    if (g == 0) {
        #pragma unroll
        for (int j = 0; j < 8; ++j)
            v[j] = f2bf(We1[j * 128 + ct * 16 + c]);
    }
    *(bf16x8*)(outL + (size_t)t * 8) = v;
}

// ---------------------------------------------------------------------------
// k_proj: per-node projections through sender/receiver blocks of We1.
// ---------------------------------------------------------------------------
__global__ __launch_bounds__(128)
void k_proj(const float* __restrict__ feat, const float* __restrict__ We1,
            float* __restrict__ FsP, float* __restrict__ FrP)
{
    __shared__ float sF[128];
    int n = blockIdx.x, j = threadIdx.x;
    sF[j] = feat[n * 128 + j];
    __syncthreads();
    float a = 0.f, b = 0.f;
    #pragma unroll 8
    for (int k = 0; k < 128; ++k) {
        float f = sF[k];
        a = fmaf(f, We1[(8   + k) * 128 + j], a);
        b = fmaf(f, We1[(136 + k) * 128 + j], b);
    }
    FsP[n * 128 + j] = a;
    FrP[n * 128 + j] = b;
}

// ---------------------------------------------------------------------------
// streamed B-fragment loader (coalesced 16B/lane, L2-hot)
// ---------------------------------------------------------------------------
__device__ __forceinline__ void loadB(const short* __restrict__ p,
                                      bf16x8 (&B)[2][4], int w, int lane)
{
    const bf16x8* p8 = (const bf16x8*)p;
    #pragma unroll
    for (int ctl = 0; ctl < 2; ++ctl)
        #pragma unroll
        for (int kt = 0; kt < 4; ++kt)
            B[ctl][kt] = p8[((w * 2 + ctl) * 4 + kt) * 64 + lane];
}

// 32x128 @ 128x128 core: A from swizzled bf16 LDS, B transient VGPRs,
// silu(scale*x), cvt_pk bf16 scatter back to LDS.
template<bool KEEP>
__device__ __forceinline__ void gemm_core(const short* sIn_, short* sOut_,
                                          const bf16x8 (&B)[2][4],
                                          const int (&adrK)[4],
                                          const int (&wAdr)[2][4],
                                          float scale, f32x4 (&keep)[2][2])
{
    const char* sIn = (const char*)sIn_;
    char* sOut = (char*)sOut_;
    const f32x4 z = {0.f, 0.f, 0.f, 0.f};
    f32x4 acc[2][2] = {{z, z}, {z, z}};
    #pragma unroll
    for (int kt = 0; kt < 4; ++kt) {
        bf16x8 a0 = *(const bf16x8*)(sIn + adrK[kt]);
        bf16x8 a1 = *(const bf16x8*)(sIn + adrK[kt] + 4096);
        acc[0][0] = MFMA16(a0, B[0][kt], acc[0][0], 0, 0, 0);
        acc[0][1] = MFMA16(a0, B[1][kt], acc[0][1], 0, 0, 0);
        acc[1][0] = MFMA16(a1, B[0][kt], acc[1][0], 0, 0, 0);
        acc[1][1] = MFMA16(a1, B[1][kt], acc[1][1], 0, 0, 0);
    }
    #pragma unroll
    for (int rt = 0; rt < 2; ++rt)
        #pragma unroll
        for (int ctl = 0; ctl < 2; ++ctl) {
            float v0 = silu_f(acc[rt][ctl][0] * scale);
            float v1 = silu_f(acc[rt][ctl][1] * scale);
            float v2 = silu_f(acc[rt][ctl][2] * scale);
            float v3 = silu_f(acc[rt][ctl][3] * scale);
            if (KEEP) {
                keep[rt][ctl][0] = v0; keep[rt][ctl][1] = v1;
                keep[rt][ctl][2] = v2; keep[rt][ctl][3] = v3;
            }
            unsigned p01, p23;
            CVT_PK(p01, v0, v1);
            CVT_PK(p23, v2, v3);
            char* o = sOut + rt * 4096;
            *(short*)(o + wAdr[ctl][0]) = (short)(p01 & 0xFFFFu);
            *(short*)(o + wAdr[ctl][1]) = (short)(p01 >> 16);
            *(short*)(o + wAdr[ctl][2]) = (short)(p23 & 0xFFFFu);
            *(short*)(o + wAdr[ctl][3]) = (short)(p23 >> 16);
        }
}

// ---------------------------------------------------------------------------
// k_edge: one block per (sender, half); 8 chunks of 32 receivers.
// All weights streamed per-use (no pinning) -> register demand < 128 cap.
// ---------------------------------------------------------------------------
__global__ __launch_bounds__(256, 4)
void k_edge(const float* __restrict__ pos,
            const float* __restrict__ Winf,
            const float* __restrict__ FsP,
            const float* __restrict__ FrP,
            const short* __restrict__ We1Lp,
            const short* __restrict__ We2p,
            const short* __restrict__ Wx1p,
            const short* __restrict__ Wx2p,
            const short* __restrict__ Wtpp,
            float* __restrict__ MI2,
            float* __restrict__ VEC2)
{
    __shared__ __align__(16) short sX[CH * 128];   // activations ping (swizzled)
    __shared__ __align__(16) short sY[CH * 128];   // activations pong
    __shared__ __align__(16) float sLS[CH * NV * 4]; // (sh.xyz, len), v-slot swizzled
    __shared__ float sWinf[8 * 17];                // stride-17
    __shared__ float sPosS[24];
    __shared__ float sE[CH];
    __shared__ float sVp[4 * 24];

    const int bid = blockIdx.x;
    const int s = bid >> 1, half = bid & 1;
    const int t = threadIdx.x;
    const int lane = t & 63, w = t >> 6;
    const int rl = lane & 15, kg = lane >> 4;

    // ---- per-thread constant LDS byte addresses ----
    const int swz = (rl & 7) << 4;
    const int ktperm = (rl & 4) << 4;
    const int baseRd = rl * 256 + ((kg * 16) ^ (swz & 0x30));
    int adrK[4];
    #pragma unroll
    for (int kt = 0; kt < 4; ++kt) adrK[kt] = baseRd + ((kt * 64) ^ ktperm);
    int wAdr[2][4];
    #pragma unroll
    for (int ctl = 0; ctl < 2; ++ctl)
        #pragma unroll
        for (int jj = 0; jj < 4; ++jj) {
            int r = kg * 4 + jj;
            wAdr[ctl][jj] = r * 256 + ((w * 64 + ctl * 32 + 2 * rl) ^ ((r & 7) << 4));
        }
    const int colg0 = w * 32 + rl, colg1 = colg0 + 16;
    const int er = t >> 3, eo = t & 7;
    const int eAdr0 = er * 256 + ((eo * 32)      ^ ((er & 7) << 4));
    const int eAdr1 = er * 256 + ((eo * 32 + 16) ^ ((er & 7) << 4));
    const int vv = w * 2 + (rl >> 3);

    if (t < 128) sWinf[(t >> 4) * 17 + (t & 15)] = Winf[t];
    if (t < 24)  sPosS[t] = pos[s * 24 + t];

    // sender projection scalars for this thread's two output columns
    const float fs0 = FsP[s * 128 + colg0];
    const float fs1 = FsP[s * 128 + colg1];

    float miacc0 = 0.f, miacc1 = 0.f;
    float vax = 0.f, vay = 0.f, vaz = 0.f;
    __syncthreads();                                              // B0

    for (int c = 0; c < NCHH; ++c) {
        const int r0 = (half * NCHH + c) * CH;

        // ---- ph0: lengths + sh1 -> sLS ----
        {
            int r = t >> 3, v = t & 7;
            const float* pr = pos + (size_t)(r0 + r) * 24 + v * 3;
            float dx = sPosS[v * 3 + 0] - pr[0];
            float dy = sPosS[v * 3 + 1] - pr[1];
            float dz = sPosS[v * 3 + 2] - pr[2];
            float sq  = dx * dx + dy * dy + dz * dz;
            float len = sqrtf(fmaxf(sq, 1e-20f));   // r==s -> dx=0 -> sh1=0
            float inv = SQRT3 / len;
            f32x4 o; o[0] = dx * inv; o[1] = dy * inv; o[2] = dz * inv; o[3] = len;
            *(f32x4*)(sLS + (r * 8 + (v ^ (r & 7))) * 4) = o;
        }
        __syncthreads();                                          // B1

        // ---- FrP loads for the L1 epilogue (transient, overlap with pack) ----
        float frv[2][2][4];
        #pragma unroll
        for (int rt = 0; rt < 2; ++rt)
            #pragma unroll
            for (int jj = 0; jj < 4; ++jj) {
                const float* fp = FrP + (size_t)(r0 + rt * 16 + kg * 4 + jj) * 128;
                frv[rt][0][jj] = fp[colg0];
                frv[rt][1][jj] = fp[colg1];
            }

        // ---- L1: lens @ We1L (K padded to 32) + fs + fr, silu -> sX ----
        {
            const bf16x8* pL = (const bf16x8*)We1Lp;
            bf16x8 bL0 = pL[(w * 2 + 0) * 64 + lane];
            bf16x8 bL1 = pL[(w * 2 + 1) * 64 + lane];
            bf16x8 aL0 = {0,0,0,0,0,0,0,0}, aL1 = {0,0,0,0,0,0,0,0};
            if (kg == 0) {
                const float* Lp = sLS + rl * 32;
                const float* Lq = sLS + (rl + 16) * 32;
                unsigned u0[4], u1[4];
                #pragma unroll
                for (int jp = 0; jp < 4; ++jp) {
                    CVT_PK(u0[jp], Lp[((2*jp)   ^ (rl & 7)) * 4 + 3],
                                   Lp[((2*jp+1) ^ (rl & 7)) * 4 + 3]);
                    CVT_PK(u1[jp], Lq[((2*jp)   ^ (rl & 7)) * 4 + 3],
                                   Lq[((2*jp+1) ^ (rl & 7)) * 4 + 3]);
                }
                uint4 v0 = {u0[0], u0[1], u0[2], u0[3]};
                uint4 v1 = {u1[0], u1[1], u1[2], u1[3]};
                aL0 = __builtin_bit_cast(bf16x8, v0);
                aL1 = __builtin_bit_cast(bf16x8, v1);
            }
            const f32x4 z = {0.f, 0.f, 0.f, 0.f};
            f32x4 aP[2][2];
            aP[0][0] = MFMA16(aL0, bL0, z, 0, 0, 0);
            aP[0][1] = MFMA16(aL0, bL1, z, 0, 0, 0);
            aP[1][0] = MFMA16(aL1, bL0, z, 0, 0, 0);
            aP[1][1] = MFMA16(aL1, bL1, z, 0, 0, 0);
            char* sXc = (char*)sX;
            #pragma unroll
            for (int rt = 0; rt < 2; ++rt)
                #pragma unroll
                for (int ctl = 0; ctl < 2; ++ctl) {
                    float fsv = ctl ? fs1 : fs0;
                    float v0 = silu_f((aP[rt][ctl][0] + fsv + frv[rt][ctl][0]) * C1);
                    float v1 = silu_f((aP[rt][ctl][1] + fsv + frv[rt][ctl][1]) * C1);
                    float v2 = silu_f((aP[rt][ctl][2] + fsv + frv[rt][ctl][2]) * C1);
                    float v3 = silu_f((aP[rt][ctl][3] + fsv + frv[rt][ctl][3]) * C1);
                    unsigned p01, p23;
                    CVT_PK(p01, v0, v1);
                    CVT_PK(p23, v2, v3);
                    char* o = sXc + rt * 4096;
                    *(short*)(o + wAdr[ctl][0]) = (short)(p01 & 0xFFFFu);
                    *(short*)(o + wAdr[ctl][1]) = (short)(p01 >> 16);
                    *(short*)(o + wAdr[ctl][2]) = (short)(p23 & 0xFFFFu);
                    *(short*)(o + wAdr[ctl][3]) = (short)(p23 >> 16);
                }
        }
        __syncthreads();                                          // B2

        // ---- L2: m_ij = silu(C2 * a1 @ We2) -> sY ; keep fp32 copies ----
        f32x4 keepM[2][2];
        {
            bf16x8 Bs[2][4];
            loadB(We2p, Bs, w, lane);
            gemm_core<true>(sX, sY, Bs, adrK, wAdr, C2, keepM);
        }
        __syncthreads();                                          // B3

        // ---- e[r] = sigmoid(C2 * m_ij . Winf)  (in-wave shfl reduce) ----
        {
            const char* sYc = (const char*)sY;
            uint4 m0 = *(const uint4*)(sYc + eAdr0);
            uint4 m1 = *(const uint4*)(sYc + eAdr1);
            const unsigned mu[8] = {m0.x, m0.y, m0.z, m0.w, m1.x, m1.y, m1.z, m1.w};
            float d = 0.f;
            #pragma unroll
            for (int q = 0; q < 8; ++q) {
                d = fmaf(bflo(mu[q]), sWinf[eo * 17 + 2 * q],     d);
                d = fmaf(bfhi(mu[q]), sWinf[eo * 17 + 2 * q + 1], d);
            }
            d += __shfl_xor(d, 1); d += __shfl_xor(d, 2); d += __shfl_xor(d, 4);
            if (eo == 0) sE[er] = (r0 + er == s) ? 0.f : sigm_f(d * C2);
        }
        __syncthreads();                                          // B4

        // ---- m_i accumulation from registers ----
        #pragma unroll
        for (int rt = 0; rt < 2; ++rt)
            #pragma unroll
            for (int jj = 0; jj < 4; ++jj) {
                float e = sE[rt * 16 + kg * 4 + jj];
                miacc0 = fmaf(keepM[rt][0][jj], e, miacc0);
                miacc1 = fmaf(keepM[rt][1][jj], e, miacc1);
            }

        // ---- phi_x layer 1 ----
        {
            bf16x8 Bs[2][4];
            loadB(Wx1p, Bs, w, lane);
            gemm_core<false>(sY, sX, Bs, adrK, wAdr, C2, keepM);
        }
        __syncthreads();                                          // B5
        // ---- phi_x layer 2 ----
        {
            bf16x8 Bs[2][4];
            loadB(Wx2p, Bs, w, lane);
            gemm_core<false>(sX, sY, Bs, adrK, wAdr, C2, keepM);
        }
        __syncthreads();                                          // B6

        // ---- TP gemm + vec acc from regs ----
        {
            const bf16x8* p8 = (const bf16x8*)Wtpp;
            const f32x4 z = {0.f, 0.f, 0.f, 0.f};
            f32x4 acc0 = z, acc1 = z;
            const char* sYc = (const char*)sY;
            #pragma unroll
            for (int kt = 0; kt < 4; ++kt) {
                bf16x8 bt = p8[(w * 4 + kt) * 64 + lane];
                bf16x8 a0 = *(const bf16x8*)(sYc + adrK[kt]);
                bf16x8 a1 = *(const bf16x8*)(sYc + adrK[kt] + 4096);
                acc0 = MFMA16(a0, bt, acc0, 0, 0, 0);
                acc1 = MFMA16(a1, bt, acc1, 0, 0, 0);
            }
            #pragma unroll
            for (int rt = 0; rt < 2; ++rt)
                #pragma unroll
                for (int jj = 0; jj < 4; ++jj) {
                    int row = rt * 16 + kg * 4 + jj;
                    const f32x4 sh = *(const f32x4*)(sLS + (row * 8 + (vv ^ (row & 7))) * 4);
                    float g = rt ? acc1[jj] : acc0[jj];
                    vax = fmaf(g, sh[0], vax);
                    vay = fmaf(g, sh[1], vay);
                    vaz = fmaf(g, sh[2], vaz);
                }
        }
        __syncthreads();                                          // B7
    }

    // ---- epilogue: m_i reduce over row-groups ----
    miacc0 += __shfl_xor(miacc0, 16); miacc0 += __shfl_xor(miacc0, 32);
    miacc1 += __shfl_xor(miacc1, 16); miacc1 += __shfl_xor(miacc1, 32);
    if (lane < 16) {
        float* mo = MI2 + (size_t)(half * NN + s) * 128;
        mo[w * 32 + lane]      = miacc0;
        mo[w * 32 + 16 + lane] = miacc1;
    }
    // ---- vec reduce ----
    vax += __shfl_xor(vax, 8);  vay += __shfl_xor(vay, 8);  vaz += __shfl_xor(vaz, 8);
    vax += __shfl_xor(vax, 16); vay += __shfl_xor(vay, 16); vaz += __shfl_xor(vaz, 16);
    vax += __shfl_xor(vax, 32); vay += __shfl_xor(vay, 32); vaz += __shfl_xor(vaz, 32);
    if ((lane & 56) == 0) {
        float* vp = sVp + w * 24 + lane * 3;
        vp[0] = vax; vp[1] = vay; vp[2] = vaz;
    }
    __syncthreads();
    if (t < 24) {
        float sum = sVp[t] + sVp[24 + t] + sVp[48 + t] + sVp[72 + t];
        VEC2[(size_t)(half * NN + s) * 24 + t] = sum * (1.0f / 32.0f);
    }
}

// ---------------------------------------------------------------------------
// k_node: per-node h-MLP + residual + position update (sums the 2 halves).
// ---------------------------------------------------------------------------
__global__ __launch_bounds__(128)
void k_node(const float* __restrict__ pos, const float* __restrict__ feat,
            const float* __restrict__ Wh1, const float* __restrict__ Wh2,
            const float* __restrict__ Wh3,
            const float* __restrict__ MI2, const float* __restrict__ VEC2,
            float* __restrict__ outPos, float* __restrict__ outFeat)
{
    __shared__ float sMi[128], sF[128], sH[128];
    int n = blockIdx.x, j = threadIdx.x;
    sMi[j] = MI2[n * 128 + j] + MI2[NN * 128 + n * 128 + j];
    sF[j]  = feat[n * 128 + j];
    __syncthreads();
    float a = 0.f;
    #pragma unroll 8
    for (int k = 0; k < 128; ++k) a = fmaf(sMi[k], Wh1[k * 128 + j], a);
    #pragma unroll 8
    for (int k = 0; k < 128; ++k) a = fmaf(sF[k], Wh1[(128 + k) * 128 + j], a);
    a = silu_f(a * 0.0625f);            // 1/sqrt(256)
    sH[j] = a;
    __syncthreads();
    float b = 0.f;
    #pragma unroll 8
    for (int k = 0; k < 128; ++k) b = fmaf(sH[k], Wh2[k * 128 + j], b);
    b = silu_f(b * C2);
    sMi[j] = b;
    __syncthreads();
    float cc = 0.f;
    #pragma unroll 8
    for (int k = 0; k < 128; ++k) cc = fmaf(sMi[k], Wh3[k * 128 + j], cc);
    outFeat[n * 128 + j] = cc * C2 + sF[j];
    if (j < 24) outPos[n * 24 + j] = pos[n * 24 + j]
                                   + VEC2[n * 24 + j] + VEC2[NN * 24 + n * 24 + j];
}

// ---------------------------------------------------------------------------
extern "C" void kernel_launch(void* const* d_in, const int* in_sizes, int n_in,
                              void* d_out, int out_size, void* d_ws, size_t ws_size,
                              hipStream_t stream) {
    const float* pos  = (const float*)d_in[0];
    const float* feat = (const float*)d_in[1];
    const float* We1  = (const float*)d_in[2];
    const float* We2  = (const float*)d_in[3];
    const float* Wx1  = (const float*)d_in[4];
    const float* Wx2  = (const float*)d_in[5];
    const float* Winf = (const float*)d_in[6];
    const float* Wtp  = (const float*)d_in[7];
    const float* Wh1  = (const float*)d_in[8];
    const float* Wh2  = (const float*)d_in[9];
    const float* Wh3  = (const float*)d_in[10];

    float* outPos  = (float*)d_out;              // [512*8*3]
    float* outFeat = (float*)d_out + NN * 24;    // [512*128]

    float* ws   = (float*)d_ws;
    float* FsP  = ws;                   // 65536 floats
    float* FrP  = ws + 65536;           // 65536
    float* MI2  = ws + 131072;          // 2*65536
    float* VEC2 = ws + 262144;          // 2*12288
    short* wpack = (short*)(ws + 286720);
    short* We2p  = wpack;               // 16384 shorts
    short* Wx1p  = wpack + 16384;       // 16384
    short* Wx2p  = wpack + 32768;       // 16384
    short* Wtpp  = wpack + 49152;       // 8192
    short* We1Lp = wpack + 57344;       // 4096   (total ws ~1.26 MB)

    k_pack<<<dim3(8), dim3(256), 0, stream>>>(We2, We2p, 128);
    k_pack<<<dim3(8), dim3(256), 0, stream>>>(Wx1, Wx1p, 128);
    k_pack<<<dim3(8), dim3(256), 0, stream>>>(Wx2, Wx2p, 128);
    k_pack<<<dim3(4), dim3(256), 0, stream>>>(Wtp, Wtpp, 64);
    k_packL<<<dim3(1), dim3(512), 0, stream>>>(We1, We1Lp);
    k_proj<<<dim3(NN), dim3(128), 0, stream>>>(feat, We1, FsP, FrP);
    k_edge<<<dim3(2 * NN), dim3(256), 0, stream>>>(pos, Winf, FsP, FrP, We1Lp,
                                                   We2p, Wx1p, Wx2p, Wtpp, MI2, VEC2);
    k_node<<<dim3(NN), dim3(128), 0, stream>>>(pos, feat, Wh1, Wh2, Wh3, MI2, VEC2,
                                               outPos, outFeat);
}

// Round 7
// 96.158 us; speedup vs baseline: 2.4444x; 1.2819x over previous
//
#include <hip/hip_runtime.h>
#include <math.h>

#define NN   512
#define NV   8
#define CH   32      // receivers per chunk
#define NCHH 8       // chunks per half-block (2 blocks per sender)

#define C1 0.06154574548966636f   // 1/sqrt(264)
#define C2 0.08838834764831845f   // 1/sqrt(128)
#define SQRT3 1.7320508075688772f

typedef __attribute__((ext_vector_type(8))) short bf16x8;   // 8 bf16 = 4 VGPRs
typedef __attribute__((ext_vector_type(4))) float f32x4;

#define MFMA16 __builtin_amdgcn_mfma_f32_16x16x32_bf16
// pack two fp32 -> one u32 of 2 bf16 (lo = a, hi = b)
#define CVT_PK(dst, a, b) asm("v_cvt_pk_bf16_f32 %0, %1, %2" : "=v"(dst) : "v"(a), "v"(b))

__device__ __forceinline__ float silu_f(float x) {
    float e = __builtin_amdgcn_exp2f(x * -1.442695041f);
    return x * __builtin_amdgcn_rcpf(1.0f + e);
}
__device__ __forceinline__ float sigm_f(float x) {
    float e = __builtin_amdgcn_exp2f(x * -1.442695041f);
    return __builtin_amdgcn_rcpf(1.0f + e);
}
__device__ __forceinline__ short f2bf(float f) {
    unsigned u = __builtin_bit_cast(unsigned, f);
    u = (u + 0x7FFFu + ((u >> 16) & 1u)) >> 16;
    return (short)u;
}
__device__ __forceinline__ float bfhi(unsigned u) {
    return __builtin_bit_cast(float, u & 0xFFFF0000u);
}
__device__ __forceinline__ float bflo(unsigned u) {
    return __builtin_bit_cast(float, u << 16);
}

// ---------------------------------------------------------------------------
// k_packall: all weight packing + k_proj fused into ONE launch.
// blocks 0-7: We2 -> frags; 8-15: Wx1; 16-23: Wx2; 24-27: Wtp (64 cols);
// 28: We1 length rows; 29..284: per-node projections (2 nodes/block).
// Frag (ct,kt), lane l, elem j holds W[32kt + (l>>4)*8 + j][16ct + (l&15)].
// ---------------------------------------------------------------------------
__device__ __forceinline__ void packW(const float* __restrict__ W,
                                      short* __restrict__ out, int ncols, int ct)
{
    int t = threadIdx.x;
    int lane = t & 63, kt = (t >> 6) & 3;
    int g = lane >> 4, c = lane & 15;
    bf16x8 v;
    #pragma unroll
    for (int j = 0; j < 8; ++j)
        v[j] = f2bf(W[(kt * 32 + g * 8 + j) * ncols + ct * 16 + c]);
    *(bf16x8*)(out + (size_t)(ct * 256 + t) * 8) = v;
}

__global__ __launch_bounds__(256)
void k_packall(const float* __restrict__ We2, const float* __restrict__ Wx1,
               const float* __restrict__ Wx2, const float* __restrict__ Wtp,
               const float* __restrict__ We1, const float* __restrict__ feat,
               short* __restrict__ We2p, short* __restrict__ Wx1p,
               short* __restrict__ Wx2p, short* __restrict__ Wtpp,
               short* __restrict__ We1Lp,
               float* __restrict__ FsP, float* __restrict__ FrP)
{
    const int b = blockIdx.x, t = threadIdx.x;
    if (b < 8)       { packW(We2, We2p, 128, b);      return; }
    if (b < 16)      { packW(Wx1, Wx1p, 128, b - 8);  return; }
    if (b < 24)      { packW(Wx2, Wx2p, 128, b - 16); return; }
    if (b < 28)      { packW(Wtp, Wtpp,  64, b - 24); return; }
    if (b == 28) {
        // B-frags of We1 rows 0..7, K padded to 32. 8 col-tiles, 2 per thread.
        #pragma unroll
        for (int h = 0; h < 2; ++h) {
            int tt = t + h * 256;
            int ct = tt >> 6, l = tt & 63, g = l >> 4, c = l & 15;
            bf16x8 v = {0,0,0,0,0,0,0,0};
            if (g == 0) {
                #pragma unroll
                for (int j = 0; j < 8; ++j)
                    v[j] = f2bf(We1[j * 128 + ct * 16 + c]);
            }
            *(bf16x8*)(We1Lp + (size_t)tt * 8) = v;
        }
        return;
    }
    // ---- proj: 2 nodes per block ----
    __shared__ float sF[256];
    const int n = (b - 29) * 2 + (t >> 7), j = t & 127, hb = t & 128;
    sF[t] = feat[n * 128 + j];
    __syncthreads();
    float a = 0.f, bb = 0.f;
    #pragma unroll 8
    for (int k = 0; k < 128; ++k) {
        float f = sF[hb + k];
        a  = fmaf(f, We1[(8   + k) * 128 + j], a);
        bb = fmaf(f, We1[(136 + k) * 128 + j], bb);
    }
    FsP[n * 128 + j] = a;
    FrP[n * 128 + j] = bb;
}

// ---------------------------------------------------------------------------
// laundered B-fragment loader: zz is an opaque 0 so the loads anchor HERE
// (prevents LICM from hoisting loop-invariant loads into pinned registers).
// ---------------------------------------------------------------------------
__device__ __forceinline__ void loadBz(const short* __restrict__ p,
                                       bf16x8 (&B)[2][4], int w, int lane)
{
    int zz = 0; asm volatile("" : "+v"(zz));
    const bf16x8* p8 = (const bf16x8*)p;
    #pragma unroll
    for (int ctl = 0; ctl < 2; ++ctl)
        #pragma unroll
        for (int kt = 0; kt < 4; ++kt)
            B[ctl][kt] = p8[((w * 2 + ctl) * 4 + kt) * 64 + lane + zz];
}

// MFMA-only part of the 32x128 @ 128x128 layer
__device__ __forceinline__ void gemm_mfma(const short* sIn_, const bf16x8 (&B)[2][4],
                                          const int (&adrK)[4], f32x4 (&acc)[2][2])
{
    const char* sIn = (const char*)sIn_;
    const f32x4 z = {0.f, 0.f, 0.f, 0.f};
    acc[0][0] = z; acc[0][1] = z; acc[1][0] = z; acc[1][1] = z;
    #pragma unroll
    for (int kt = 0; kt < 4; ++kt) {
        bf16x8 a0 = *(const bf16x8*)(sIn + adrK[kt]);
        bf16x8 a1 = *(const bf16x8*)(sIn + adrK[kt] + 4096);
        acc[0][0] = MFMA16(a0, B[0][kt], acc[0][0], 0, 0, 0);
        acc[0][1] = MFMA16(a0, B[1][kt], acc[0][1], 0, 0, 0);
        acc[1][0] = MFMA16(a1, B[0][kt], acc[1][0], 0, 0, 0);
        acc[1][1] = MFMA16(a1, B[1][kt], acc[1][1], 0, 0, 0);
    }
}

// epilogue: silu(scale*acc) -> bf16 scatter into LDS (optionally keep fp32)
template<bool KEEP>
__device__ __forceinline__ void epi_store(const f32x4 (&acc)[2][2], short* sOut_,
                                          const int (&wAdr)[2][4], float scale,
                                          f32x4 (&keep)[2][2])
{
    char* sOut = (char*)sOut_;
    #pragma unroll
    for (int rt = 0; rt < 2; ++rt)
        #pragma unroll
        for (int ctl = 0; ctl < 2; ++ctl) {
            float v0 = silu_f(acc[rt][ctl][0] * scale);
            float v1 = silu_f(acc[rt][ctl][1] * scale);
            float v2 = silu_f(acc[rt][ctl][2] * scale);
            float v3 = silu_f(acc[rt][ctl][3] * scale);
            if (KEEP) {
                keep[rt][ctl][0] = v0; keep[rt][ctl][1] = v1;
                keep[rt][ctl][2] = v2; keep[rt][ctl][3] = v3;
            }
            unsigned p01, p23;
            CVT_PK(p01, v0, v1);
            CVT_PK(p23, v2, v3);
            char* o = sOut + rt * 4096;
            *(short*)(o + wAdr[ctl][0]) = (short)(p01 & 0xFFFFu);
            *(short*)(o + wAdr[ctl][1]) = (short)(p01 >> 16);
            *(short*)(o + wAdr[ctl][2]) = (short)(p23 & 0xFFFFu);
            *(short*)(o + wAdr[ctl][3]) = (short)(p23 >> 16);
        }
}

// ---------------------------------------------------------------------------
// k_edge: one block per (sender, half); 8 chunks of 32 receivers.
// Weights streamed with issue-early/consume-late placement (no pinning).
// ---------------------------------------------------------------------------
__global__ __launch_bounds__(256, 4)
void k_edge(const float* __restrict__ pos,
            const float* __restrict__ Winf,
            const float* __restrict__ FsP,
            const float* __restrict__ FrP,
            const short* __restrict__ We1Lp,
            const short* __restrict__ We2p,
            const short* __restrict__ Wx1p,
            const short* __restrict__ Wx2p,
            const short* __restrict__ Wtpp,
            float* __restrict__ MI2,
            float* __restrict__ VEC2)
{
    __shared__ __align__(16) short sX[CH * 128];     // activations ping (swizzled)
    __shared__ __align__(16) short sY[CH * 128];     // activations pong
    __shared__ __align__(16) float sLS[CH * NV * 4]; // (sh.xyz, len), v-slot swizzled
    __shared__ float sWinf[8 * 17];
    __shared__ float sPosS[24];
    __shared__ float sE[CH];
    __shared__ float sVp[4 * 24];

    const int bid = blockIdx.x;
    const int s = bid >> 1, half = bid & 1;
    const int t = threadIdx.x;
    const int lane = t & 63, w = t >> 6;
    const int rl = lane & 15, kg = lane >> 4;

    // ---- per-thread constant LDS byte addresses ----
    const int swz = (rl & 7) << 4;
    const int ktperm = (rl & 4) << 4;
    const int baseRd = rl * 256 + ((kg * 16) ^ (swz & 0x30));
    int adrK[4];
    #pragma unroll
    for (int kt = 0; kt < 4; ++kt) adrK[kt] = baseRd + ((kt * 64) ^ ktperm);
    int wAdr[2][4];
    #pragma unroll
    for (int ctl = 0; ctl < 2; ++ctl)
        #pragma unroll
        for (int jj = 0; jj < 4; ++jj) {
            int r = kg * 4 + jj;
            wAdr[ctl][jj] = r * 256 + ((w * 64 + ctl * 32 + 2 * rl) ^ ((r & 7) << 4));
        }
    const int colg0 = w * 32 + rl, colg1 = colg0 + 16;
    const int er = t >> 3, eo = t & 7;
    const int eAdr0 = er * 256 + ((eo * 32)      ^ ((er & 7) << 4));
    const int eAdr1 = er * 256 + ((eo * 32 + 16) ^ ((er & 7) << 4));
    const int vv = w * 2 + (rl >> 3);

    if (t < 128) sWinf[(t >> 4) * 17 + (t & 15)] = Winf[t];
    if (t < 24)  sPosS[t] = pos[s * 24 + t];

    const float fs0 = FsP[s * 128 + colg0];
    const float fs1 = FsP[s * 128 + colg1];

    float miacc0 = 0.f, miacc1 = 0.f;
    float vax = 0.f, vay = 0.f, vaz = 0.f;
    __syncthreads();                                              // B0

    for (int c = 0; c < NCHH; ++c) {
        const int r0 = (half * NCHH + c) * CH;

        // ==== chunk-top issue: We2 frags + We1L frags + FrP (hidden under ph0) ====
        bf16x8 Bw[2][4];
        loadBz(We2p, Bw, w, lane);
        bf16x8 bL0, bL1;
        {
            int zz = 0; asm volatile("" : "+v"(zz));
            const bf16x8* pL = (const bf16x8*)We1Lp;
            bL0 = pL[(w * 2 + 0) * 64 + lane + zz];
            bL1 = pL[(w * 2 + 1) * 64 + lane + zz];
        }
        float frv[2][2][4];
        {
            int zz = 0; asm volatile("" : "+v"(zz));
            #pragma unroll
            for (int rt = 0; rt < 2; ++rt)
                #pragma unroll
                for (int jj = 0; jj < 4; ++jj) {
                    const float* fp = FrP + (size_t)(r0 + rt * 16 + kg * 4 + jj) * 128 + zz;
                    frv[rt][0][jj] = fp[colg0];
                    frv[rt][1][jj] = fp[colg1];
                }
        }

        // ---- ph0: lengths + sh1 -> sLS ----
        {
            int r = t >> 3, v = t & 7;
            const float* pr = pos + (size_t)(r0 + r) * 24 + v * 3;
            float dx = sPosS[v * 3 + 0] - pr[0];
            float dy = sPosS[v * 3 + 1] - pr[1];
            float dz = sPosS[v * 3 + 2] - pr[2];
            float sq  = dx * dx + dy * dy + dz * dz;
            float len = sqrtf(fmaxf(sq, 1e-20f));   // r==s -> dx=0 -> sh1=0
            float inv = SQRT3 / len;
            f32x4 o; o[0] = dx * inv; o[1] = dy * inv; o[2] = dz * inv; o[3] = len;
            *(f32x4*)(sLS + (r * 8 + (v ^ (r & 7))) * 4) = o;
        }
        __syncthreads();                                          // B1

        // ---- L1: lens @ We1L + fs + fr, silu -> sX ----
        {
            bf16x8 aL0 = {0,0,0,0,0,0,0,0}, aL1 = {0,0,0,0,0,0,0,0};
            if (kg == 0) {
                const float* Lp = sLS + rl * 32;
                const float* Lq = sLS + (rl + 16) * 32;
                unsigned u0[4], u1[4];
                #pragma unroll
                for (int jp = 0; jp < 4; ++jp) {
                    CVT_PK(u0[jp], Lp[((2*jp)   ^ (rl & 7)) * 4 + 3],
                                   Lp[((2*jp+1) ^ (rl & 7)) * 4 + 3]);
                    CVT_PK(u1[jp], Lq[((2*jp)   ^ (rl & 7)) * 4 + 3],
                                   Lq[((2*jp+1) ^ (rl & 7)) * 4 + 3]);
                }
                uint4 v0 = {u0[0], u0[1], u0[2], u0[3]};
                uint4 v1 = {u1[0], u1[1], u1[2], u1[3]};
                aL0 = __builtin_bit_cast(bf16x8, v0);
                aL1 = __builtin_bit_cast(bf16x8, v1);
            }
            const f32x4 z = {0.f, 0.f, 0.f, 0.f};
            f32x4 aP[2][2];
            aP[0][0] = MFMA16(aL0, bL0, z, 0, 0, 0);
            aP[0][1] = MFMA16(aL0, bL1, z, 0, 0, 0);
            aP[1][0] = MFMA16(aL1, bL0, z, 0, 0, 0);
            aP[1][1] = MFMA16(aL1, bL1, z, 0, 0, 0);
            char* sXc = (char*)sX;
            #pragma unroll
            for (int rt = 0; rt < 2; ++rt)
                #pragma unroll
                for (int ctl = 0; ctl < 2; ++ctl) {
                    float fsv = ctl ? fs1 : fs0;
                    float v0 = silu_f((aP[rt][ctl][0] + fsv + frv[rt][ctl][0]) * C1);
                    float v1 = silu_f((aP[rt][ctl][1] + fsv + frv[rt][ctl][1]) * C1);
                    float v2 = silu_f((aP[rt][ctl][2] + fsv + frv[rt][ctl][2]) * C1);
                    float v3 = silu_f((aP[rt][ctl][3] + fsv + frv[rt][ctl][3]) * C1);
                    unsigned p01, p23;
                    CVT_PK(p01, v0, v1);
                    CVT_PK(p23, v2, v3);
                    char* o = sXc + rt * 4096;
                    *(short*)(o + wAdr[ctl][0]) = (short)(p01 & 0xFFFFu);
                    *(short*)(o + wAdr[ctl][1]) = (short)(p01 >> 16);
                    *(short*)(o + wAdr[ctl][2]) = (short)(p23 & 0xFFFFu);
                    *(short*)(o + wAdr[ctl][3]) = (short)(p23 >> 16);
                }
        }
        __syncthreads();                                          // B2

        // ---- L2: m_ij = silu(C2 * a1 @ We2) -> sY ; Wx1 issued under epilogue ----
        f32x4 acc[2][2];
        f32x4 keepM[2][2];
        gemm_mfma(sX, Bw, adrK, acc);          // consumes We2 (Bw regs die)
        bf16x8 Bn[2][4];
        loadBz(Wx1p, Bn, w, lane);             // Wx1 in flight: epi + e-phase
        epi_store<true>(acc, sY, wAdr, C2, keepM);
        __syncthreads();                                          // B3

        // ---- e[r] = sigmoid(C2 * m_ij . Winf) ----
        {
            const char* sYc = (const char*)sY;
            uint4 m0 = *(const uint4*)(sYc + eAdr0);
            uint4 m1 = *(const uint4*)(sYc + eAdr1);
            const unsigned mu[8] = {m0.x, m0.y, m0.z, m0.w, m1.x, m1.y, m1.z, m1.w};
            float d = 0.f;
            #pragma unroll
            for (int q = 0; q < 8; ++q) {
                d = fmaf(bflo(mu[q]), sWinf[eo * 17 + 2 * q],     d);
                d = fmaf(bfhi(mu[q]), sWinf[eo * 17 + 2 * q + 1], d);
            }
            d += __shfl_xor(d, 1); d += __shfl_xor(d, 2); d += __shfl_xor(d, 4);
            if (eo == 0) sE[er] = (r0 + er == s) ? 0.f : sigm_f(d * C2);
        }
        __syncthreads();                                          // B4

        // ---- m_i accumulation from registers ----
        #pragma unroll
        for (int rt = 0; rt < 2; ++rt)
            #pragma unroll
            for (int jj = 0; jj < 4; ++jj) {
                float e = sE[rt * 16 + kg * 4 + jj];
                miacc0 = fmaf(keepM[rt][0][jj], e, miacc0);
                miacc1 = fmaf(keepM[rt][1][jj], e, miacc1);
            }

        // ---- L3: phi_x layer 1 ; Wx2 issued under epilogue ----
        gemm_mfma(sY, Bn, adrK, acc);          // consumes Wx1
        loadBz(Wx2p, Bw, w, lane);             // Wx2 in flight: epi + barrier
        epi_store<false>(acc, sX, wAdr, C2, keepM);
        __syncthreads();                                          // B5

        // ---- L4: phi_x layer 2 ; Wtp issued under epilogue ----
        gemm_mfma(sX, Bw, adrK, acc);          // consumes Wx2
        bf16x8 Bt[4];
        {
            int zz = 0; asm volatile("" : "+v"(zz));
            const bf16x8* p8 = (const bf16x8*)Wtpp;
            #pragma unroll
            for (int kt = 0; kt < 4; ++kt) Bt[kt] = p8[(w * 4 + kt) * 64 + lane + zz];
        }
        epi_store<false>(acc, sY, wAdr, C2, keepM);
        __syncthreads();                                          // B6

        // ---- TP gemm + vec acc from regs ----
        {
            const f32x4 z = {0.f, 0.f, 0.f, 0.f};
            f32x4 acc0 = z, acc1 = z;
            const char* sYc = (const char*)sY;
            #pragma unroll
            for (int kt = 0; kt < 4; ++kt) {
                bf16x8 a0 = *(const bf16x8*)(sYc + adrK[kt]);
                bf16x8 a1 = *(const bf16x8*)(sYc + adrK[kt] + 4096);
                acc0 = MFMA16(a0, Bt[kt], acc0, 0, 0, 0);
                acc1 = MFMA16(a1, Bt[kt], acc1, 0, 0, 0);
            }
            #pragma unroll
            for (int rt = 0; rt < 2; ++rt)
                #pragma unroll
                for (int jj = 0; jj < 4; ++jj) {
                    int row = rt * 16 + kg * 4 + jj;
                    const f32x4 sh = *(const f32x4*)(sLS + (row * 8 + (vv ^ (row & 7))) * 4);
                    float g = rt ? acc1[jj] : acc0[jj];
                    vax = fmaf(g, sh[0], vax);
                    vay = fmaf(g, sh[1], vay);
                    vaz = fmaf(g, sh[2], vaz);
                }
        }
        __syncthreads();                                          // B7
    }

    // ---- epilogue: m_i reduce over row-groups ----
    miacc0 += __shfl_xor(miacc0, 16); miacc0 += __shfl_xor(miacc0, 32);
    miacc1 += __shfl_xor(miacc1, 16); miacc1 += __shfl_xor(miacc1, 32);
    if (lane < 16) {
        float* mo = MI2 + (size_t)(half * NN + s) * 128;
        mo[w * 32 + lane]      = miacc0;
        mo[w * 32 + 16 + lane] = miacc1;
    }
    // ---- vec reduce ----
    vax += __shfl_xor(vax, 8);  vay += __shfl_xor(vay, 8);  vaz += __shfl_xor(vaz, 8);
    vax += __shfl_xor(vax, 16); vay += __shfl_xor(vay, 16); vaz += __shfl_xor(vaz, 16);
    vax += __shfl_xor(vax, 32); vay += __shfl_xor(vay, 32); vaz += __shfl_xor(vaz, 32);
    if ((lane & 56) == 0) {
        float* vp = sVp + w * 24 + lane * 3;
        vp[0] = vax; vp[1] = vay; vp[2] = vaz;
    }
    __syncthreads();
    if (t < 24) {
        float sum = sVp[t] + sVp[24 + t] + sVp[48 + t] + sVp[72 + t];
        VEC2[(size_t)(half * NN + s) * 24 + t] = sum * (1.0f / 32.0f);
    }
}

// ---------------------------------------------------------------------------
// k_node: per-node h-MLP + residual + position update (sums the 2 halves).
// ---------------------------------------------------------------------------
__global__ __launch_bounds__(128)
void k_node(const float* __restrict__ pos, const float* __restrict__ feat,
            const float* __restrict__ Wh1, const float* __restrict__ Wh2,
            const float* __restrict__ Wh3,
            const float* __restrict__ MI2, const float* __restrict__ VEC2,
            float* __restrict__ outPos, float* __restrict__ outFeat)
{
    __shared__ float sMi[128], sF[128], sH[128];
    int n = blockIdx.x, j = threadIdx.x;
    sMi[j] = MI2[n * 128 + j] + MI2[NN * 128 + n * 128 + j];
    sF[j]  = feat[n * 128 + j];
    __syncthreads();
    float a = 0.f;
    #pragma unroll 8
    for (int k = 0; k < 128; ++k) a = fmaf(sMi[k], Wh1[k * 128 + j], a);
    #pragma unroll 8
    for (int k = 0; k < 128; ++k) a = fmaf(sF[k], Wh1[(128 + k) * 128 + j], a);
    a = silu_f(a * 0.0625f);            // 1/sqrt(256)
    sH[j] = a;
    __syncthreads();
    float b = 0.f;
    #pragma unroll 8
    for (int k = 0; k < 128; ++k) b = fmaf(sH[k], Wh2[k * 128 + j], b);
    b = silu_f(b * C2);
    sMi[j] = b;
    __syncthreads();
    float cc = 0.f;
    #pragma unroll 8
    for (int k = 0; k < 128; ++k) cc = fmaf(sMi[k], Wh3[k * 128 + j], cc);
    outFeat[n * 128 + j] = cc * C2 + sF[j];
    if (j < 24) outPos[n * 24 + j] = pos[n * 24 + j]
                                   + VEC2[n * 24 + j] + VEC2[NN * 24 + n * 24 + j];
}

// ---------------------------------------------------------------------------
extern "C" void kernel_launch(void* const* d_in, const int* in_sizes, int n_in,
                              void* d_out, int out_size, void* d_ws, size_t ws_size,
                              hipStream_t stream) {
    const float* pos  = (const float*)d_in[0];
    const float* feat = (const float*)d_in[1];
    const float* We1  = (const float*)d_in[2];
    const float* We2  = (const float*)d_in[3];
    const float* Wx1  = (const float*)d_in[4];
    const float* Wx2  = (const float*)d_in[5];
    const float* Winf = (const float*)d_in[6];
    const float* Wtp  = (const float*)d_in[7];
    const float* Wh1  = (const float*)d_in[8];
    const float* Wh2  = (const float*)d_in[9];
    const float* Wh3  = (const float*)d_in[10];

    float* outPos  = (float*)d_out;              // [512*8*3]
    float* outFeat = (float*)d_out + NN * 24;    // [512*128]

    float* ws   = (float*)d_ws;
    float* FsP  = ws;                   // 65536 floats
    float* FrP  = ws + 65536;           // 65536
    float* MI2  = ws + 131072;          // 2*65536
    float* VEC2 = ws + 262144;          // 2*12288
    short* wpack = (short*)(ws + 286720);
    short* We2p  = wpack;               // 16384 shorts
    short* Wx1p  = wpack + 16384;       // 16384
    short* Wx2p  = wpack + 32768;       // 16384
    short* Wtpp  = wpack + 49152;       // 8192
    short* We1Lp = wpack + 57344;       // 4096   (total ws ~1.26 MB)

    k_packall<<<dim3(285), dim3(256), 0, stream>>>(We2, Wx1, Wx2, Wtp, We1, feat,
                                                   We2p, Wx1p, Wx2p, Wtpp, We1Lp,
                                                   FsP, FrP);
    k_edge<<<dim3(2 * NN), dim3(256), 0, stream>>>(pos, Winf, FsP, FrP, We1Lp,
                                                   We2p, Wx1p, Wx2p, Wtpp, MI2, VEC2);
    k_node<<<dim3(NN), dim3(128), 0, stream>>>(pos, feat, Wh1, Wh2, Wh3, MI2, VEC2,
                                               outPos, outFeat);
}